// Round 1
// 8336.947 us; speedup vs baseline: 2.8405x; 2.8405x over previous
//
#include <hip/hip_runtime.h>
#include <stdint.h>

typedef __bf16 bf16x8 __attribute__((ext_vector_type(8)));
typedef float f32x4 __attribute__((ext_vector_type(4)));
typedef unsigned short ushort_t;

__device__ __forceinline__ float b2f(ushort_t u) {
  union { unsigned int i; float f; } x; x.i = ((unsigned int)u) << 16; return x.f;
}
__device__ __forceinline__ ushort_t f2b(float f) {
  union { float f; unsigned int i; } x; x.f = f;
  unsigned int r = x.i + 0x7fffu + ((x.i >> 16) & 1u);
  return (ushort_t)(r >> 16);
}
__device__ __forceinline__ float b2f_elem(ushort4 v, int j) {
  const ushort_t u = (j == 0) ? v.x : (j == 1) ? v.y : (j == 2) ? v.z : v.w;
  return b2f(u);
}
// fast tanh: 1 - 2/(e^{2x}+1); exact saturation at +/-inf, ~1e-6 abs error.
__device__ __forceinline__ float ftanh(float x) {
  const float e2 = __expf(2.f * x);
  return 1.f - 2.f / (e2 + 1.f);
}

// ---------------------------------------------------------------------------
// f32 -> bf16 downcast, 4 elements/thread. n4 = element_count / 4.
// ---------------------------------------------------------------------------
__global__ __launch_bounds__(256) void cvt_f32_bf16(const float* __restrict__ src,
                                                    ushort_t* __restrict__ dst,
                                                    int n4)
{
  const int i = blockIdx.x * 256 + threadIdx.x;
  if (i >= n4) return;
  const float4 v = ((const float4*)src)[i];
  ushort4 o;
  o.x = f2b(v.x); o.y = f2b(v.y); o.z = f2b(v.z); o.w = f2b(v.w);
  ((ushort4*)dst)[i] = o;
}

// ---------------------------------------------------------------------------
// dec chunk (bf16 [T*64,128]) from f32 mels: row gr = t0*64+(i>>5);
// dec[gr] = (gr<64) ? 0 : bf16(mels[gr-64]). 4 elems/thread, n4 = T*2048.
// ---------------------------------------------------------------------------
__global__ __launch_bounds__(256) void build_decin(const float* __restrict__ mels,
                                                   ushort_t* __restrict__ dec,
                                                   int t0, int n4)
{
  const int i = blockIdx.x * 256 + threadIdx.x;
  if (i >= n4) return;
  const int gr = t0 * 64 + (i >> 5);
  ushort4 o;
  if (gr < 64) {
    o.x = o.y = o.z = o.w = 0;
  } else {
    const float4 v = ((const float4*)mels)[(size_t)(gr - 64) * 32 + (i & 31)];
    o.x = f2b(v.x); o.y = f2b(v.y); o.z = f2b(v.z); o.w = f2b(v.w);
  }
  ((ushort4*)dec)[i] = o;
}

// ---------------------------------------------------------------------------
// C = [A1|A2] @ B^T + bias1 + bias2 (f32 biases), optional relu.
// A,B bf16; f32 accumulate; C written bf16 (out_f32=0) or f32 (out_f32=1).
// Tiles 128x128, BK=64, 4 waves. LDS rows padded to 72 elems.
// ---------------------------------------------------------------------------
__global__ __launch_bounds__(256) void gemm_bt(
    const ushort_t* __restrict__ A1, int lda1, int K1,
    const ushort_t* __restrict__ A2, int lda2, int K2,
    const ushort_t* __restrict__ B,
    const float* __restrict__ bias1, const float* __restrict__ bias2,
    void* __restrict__ C, int ldc, int relu, int out_f32)
{
  __shared__ __align__(16) ushort_t As[128 * 72];
  __shared__ __align__(16) ushort_t Bs[128 * 72];
  const int tid = threadIdx.x;
  const int wave = tid >> 6, lane = tid & 63;
  const int bm = blockIdx.x, bn = blockIdx.y;
  const int wm = (wave & 1) * 64, wn = (wave >> 1) * 64;
  const int l15 = lane & 15, quad = lane >> 4;
  const int ldb = K1 + K2;

  f32x4 acc[4][4] = {};

  const int kb1 = K1 >> 6, kb2 = K2 >> 6;
  for (int kb = 0; kb < kb1 + kb2; ++kb) {
    const bool ph2 = (kb >= kb1);
    const ushort_t* Aptr = ph2 ? A2 : A1;
    const int lda = ph2 ? lda2 : lda1;
    const int k0 = ph2 ? ((kb - kb1) << 6) : (kb << 6);
    const int bk0 = ph2 ? (K1 + k0) : k0;

#pragma unroll
    for (int s = 0; s < 4; ++s) {
      const int ch = s * 256 + tid;
      const int row = ch >> 3, pos = ch & 7;
      const bf16x8 av = *(const bf16x8*)(Aptr + (size_t)(bm * 128 + row) * lda
                                         + k0 + pos * 8);
      *(bf16x8*)(As + row * 72 + pos * 8) = av;
      const bf16x8 bv = *(const bf16x8*)(B + (size_t)(bn * 128 + row) * ldb
                                         + bk0 + pos * 8);
      *(bf16x8*)(Bs + row * 72 + pos * 8) = bv;
    }
    __syncthreads();

#pragma unroll
    for (int ks = 0; ks < 2; ++ks) {
      bf16x8 af[4], bfr[4];
      const int c = ks * 4 + quad;
#pragma unroll
      for (int mt = 0; mt < 4; ++mt)
        af[mt] = *(const bf16x8*)(As + (wm + mt * 16 + l15) * 72 + c * 8);
#pragma unroll
      for (int nt = 0; nt < 4; ++nt)
        bfr[nt] = *(const bf16x8*)(Bs + (wn + nt * 16 + l15) * 72 + c * 8);
#pragma unroll
      for (int mt = 0; mt < 4; ++mt)
#pragma unroll
        for (int nt = 0; nt < 4; ++nt)
          acc[mt][nt] = __builtin_amdgcn_mfma_f32_16x16x32_bf16(
              af[mt], bfr[nt], acc[mt][nt], 0, 0, 0);
    }
    __syncthreads();
  }

#pragma unroll
  for (int nt = 0; nt < 4; ++nt) {
    const int n = bn * 128 + wn + nt * 16 + l15;
    float bsum = 0.f;
    if (bias1) bsum += bias1[n];
    if (bias2) bsum += bias2[n];
#pragma unroll
    for (int mt = 0; mt < 4; ++mt) {
#pragma unroll
      for (int r = 0; r < 4; ++r) {
        const int m = bm * 128 + wm + mt * 16 + quad * 4 + r;
        float v = acc[mt][nt][r] + bsum;
        if (relu) v = fmaxf(v, 0.f);
        if (out_f32) ((float*)C)[(size_t)m * ldc + n] = v;
        else         ((ushort_t*)C)[(size_t)m * ldc + n] = f2b(v);
      }
    }
  }
}

// ---------------------------------------------------------------------------
// Persistent LSTM recurrence over T steps. 64 blocks x 256 threads.
// Block nb owns d-slice ds=nb*16 of all 4 gates. K-SPLIT across waves:
// wave g computes ALL 4 gates over K-quarter [g*256, g*256+256), with its
// W slice held in 128 VGPRs, reading h A-fragments DIRECTLY from global
// (L2/IF$-resident; cold lines per step => always fresh). Cross-wave f32
// reduce through a 35 KB LDS buffer (2 gates/round). c state lives in
// registers for the whole launch.
// Step boundary (no contended RMW, no threadfence/wbl2):
//   h stores  = agent-scope RELAXED atomic stores (write-through to IF$)
//   __syncthreads (implicit vmcnt(0) per wave drains them)
//   tid0 sets flags[s][nb] = chunk+1 (monotonic -> no reset, no WAR)
//   readers poll the 64-flag vector (1 lane each) with RELAXED agent loads.
// ---------------------------------------------------------------------------
__global__ __launch_bounds__(256, 1) void lstm_persist(
    const ushort_t* __restrict__ gates,  // [T*64, 4096] bf16
    const ushort_t* __restrict__ Whh,    // [4096, 1024] bf16
    ushort_t* __restrict__ hs,           // [(T+1)*64, 1024] bf16
    float* __restrict__ cst,             // [64, 1024] f32, persistent
    int T, int* __restrict__ flags,      // [200*64] int, monotonic
    int expect)                          // chunk index + 1
{
  __shared__ float red[4][2][64][17];    // [wave][gate-of-round][b][dl(pad)]
  const int tid = threadIdx.x;
  const int g = tid >> 6, lane = tid & 63;
  const int l15 = lane & 15, quad = lane >> 4;
  const int nb = blockIdx.x;
  const int ds = nb * 16;

  // W fragments: wave g owns K-quarter [g*256, +256) for all 4 gates.
  // warr[gg][ks] = Whh[gg*1024+ds+l15][g*256 + ks*32 + quad*8 ..+8]
  bf16x8 warr[4][8];
#pragma unroll
  for (int gg = 0; gg < 4; ++gg) {
    const ushort_t* wrow =
        Whh + (size_t)(gg * 1024 + ds + l15) * 1024 + g * 256 + quad * 8;
#pragma unroll
    for (int ks = 0; ks < 8; ++ks)
      warr[gg][ks] = *(const bf16x8*)(wrow + ks * 32);
  }

  // c state in registers: thread owns (b = tid>>2, d = ds + (tid&3)*4 ..+4)
  const int eb = tid >> 2, edl = (tid & 3) * 4;
  f32x4 creg = *(const f32x4*)(cst + eb * 1024 + ds + edl);

  for (int s = 0; s < T; ++s) {
    // 1. prefetch gates_x contributions (independent of h -> before poll)
    const ushort_t* gx_t =
        gates + (size_t)s * 262144 + (size_t)eb * 4096 + ds + edl;
    const ushort4 gxv0 = *(const ushort4*)(gx_t);
    const ushort4 gxv1 = *(const ushort4*)(gx_t + 1024);
    const ushort4 gxv2 = *(const ushort4*)(gx_t + 2048);
    const ushort4 gxv3 = *(const ushort4*)(gx_t + 3072);
    asm volatile("" ::: "memory");

    // 2. wait for h[s]: all 64 per-block flags of step s-1 (lane i -> block i)
    if (s > 0) {
      int* fp = flags + (s - 1) * 64 + lane;
      int v = __hip_atomic_load(fp, __ATOMIC_RELAXED, __HIP_MEMORY_SCOPE_AGENT);
      while (!__all(v == expect)) {
        __builtin_amdgcn_s_sleep(1);
        v = __hip_atomic_load(fp, __ATOMIC_RELAXED, __HIP_MEMORY_SCOPE_AGENT);
      }
      asm volatile("" ::: "memory");
    }

    // 3. gates partial = h[s] @ Whh_slice^T over this wave's K-quarter.
    //    A-frags straight from global (cold lines; L2/IF$ resident).
    const ushort_t* hb =
        hs + (size_t)s * 65536 + l15 * 1024 + g * 256 + quad * 8;
    f32x4 acc[4][4] = {};  // [gg][mt]
#pragma unroll
    for (int ks = 0; ks < 8; ++ks) {
      bf16x8 a[4];
#pragma unroll
      for (int mt = 0; mt < 4; ++mt)
        a[mt] = *(const bf16x8*)(hb + mt * 16384 + ks * 32);
#pragma unroll
      for (int gg = 0; gg < 4; ++gg)
#pragma unroll
        for (int mt = 0; mt < 4; ++mt)
          acc[gg][mt] = __builtin_amdgcn_mfma_f32_16x16x32_bf16(
              a[mt], warr[gg][ks], acc[gg][mt], 0, 0, 0);
    }

    // 4. cross-wave reduce, 2 gates per round (35 KB LDS)
    float gf4[4][4];
#pragma unroll
    for (int rnd = 0; rnd < 2; ++rnd) {
#pragma unroll
      for (int ggl = 0; ggl < 2; ++ggl) {
        const int gg = rnd * 2 + ggl;
#pragma unroll
        for (int mt = 0; mt < 4; ++mt)
#pragma unroll
          for (int r = 0; r < 4; ++r)
            red[g][ggl][mt * 16 + quad * 4 + r][l15] = acc[gg][mt][r];
      }
      __syncthreads();
#pragma unroll
      for (int ggl = 0; ggl < 2; ++ggl)
#pragma unroll
        for (int j = 0; j < 4; ++j)
          gf4[rnd * 2 + ggl][j] =
              red[0][ggl][eb][edl + j] + red[1][ggl][eb][edl + j] +
              red[2][ggl][eb][edl + j] + red[3][ggl][eb][edl + j];
      if (rnd == 0) __syncthreads();  // guard buffer reuse for round 1
      // (no trailing sync: next reuse is next step, ordered via flag-wait)
    }

    // 5. cell update (c in regs) + h slice store (write-through, agent scope)
    ushort_t* hdst = hs + (size_t)(s + 1) * 65536 + eb * 1024 + ds + edl;
    union { ushort_t u[4]; unsigned long long ll; } pk;
#pragma unroll
    for (int j = 0; j < 4; ++j) {
      const float gi = gf4[0][j] + b2f_elem(gxv0, j);
      const float gf = gf4[1][j] + b2f_elem(gxv1, j);
      const float gc = gf4[2][j] + b2f_elem(gxv2, j);
      const float go = gf4[3][j] + b2f_elem(gxv3, j);
      const float si = 1.f / (1.f + __expf(-gi));
      const float sf = 1.f / (1.f + __expf(-gf));
      const float so = 1.f / (1.f + __expf(-go));
      const float cn = sf * creg[j] + si * ftanh(gc);
      creg[j] = cn;
      pk.u[j] = f2b(so * ftanh(cn));
    }
    __hip_atomic_store((unsigned long long*)hdst, pk.ll,
                       __ATOMIC_RELAXED, __HIP_MEMORY_SCOPE_AGENT);

    // 6. publish: barrier drains each wave's stores (implicit vmcnt(0)),
    //    then one flag store. Readers see flag => data already at IF$.
    __syncthreads();
    if (tid == 0)
      __hip_atomic_store(flags + s * 64 + nb, expect,
                         __ATOMIC_RELAXED, __HIP_MEMORY_SCOPE_AGENT);
  }

  *(f32x4*)(cst + eb * 1024 + ds + edl) = creg;  // persist c (kernel-end flush)
}

extern "C" void kernel_launch(void* const* d_in, const int* in_sizes, int n_in,
                              void* d_out, int out_size, void* d_ws, size_t ws_size,
                              hipStream_t stream) {
  // All inputs are float32 (reference dtype); internal compute is bf16.
  const float* enc   = (const float*)d_in[0];   // [1000,64,512]
  const float* mels  = (const float*)d_in[1];   // [1000,64,128]
  const float* preW1 = (const float*)d_in[2];   // [256,128]
  const float* preb1 = (const float*)d_in[3];
  const float* preW2 = (const float*)d_in[4];   // [256,256]
  const float* preb2 = (const float*)d_in[5];
  const float* Wih   = (const float*)d_in[6];   // [4096,768]
  const float* Whh   = (const float*)d_in[7];   // [4096,1024]
  const float* bih   = (const float*)d_in[8];
  const float* bhh   = (const float*)d_in[9];
  const float* projW = (const float*)d_in[10];  // [128,1536]
  const float* projb = (const float*)d_in[11];
  float* out = (float*)d_out;                   // [1000,64,128] f32

  // chunk length T: largest even divisor of 1000 whose buffers fit ws_size
  const size_t fixedB = 32768 * 2 + 65536 * 2 + 3145728 * 2 + 4194304 * 2
                      + 196608 * 2 + 262144 + 51456 + 65536;  // weights+cst+flags+slack
  const int cand[5] = {200, 100, 50, 10, 2};
  int T = 2;
  for (int ci = 0; ci < 5; ++ci) {
    const int t = cand[ci];
    size_t need = fixedB
                + (size_t)t * 524288            // gates bf16 [T*64,4096]
                + (size_t)t * 16384             // decin bf16 [T*64,128]
                + (size_t)t * 65536             // enc_c bf16 [T*64,512]
                + (size_t)t * 32768 * 2         // x1,x2 bf16 [T*64,256]
                + (size_t)(t + 1) * 131072;     // hs bf16 [(T+1)*64,1024]
    if (need <= ws_size) { T = t; break; }
  }

  char* ws = (char*)d_ws;
  size_t off = 0;
  auto carve = [&](size_t bytes) {
    char* p = ws + off;
    off += (bytes + 255) & ~(size_t)255;
    return p;
  };
  ushort_t* wW1  = (ushort_t*)carve(32768 * 2);
  ushort_t* wW2  = (ushort_t*)carve(65536 * 2);
  ushort_t* wIh  = (ushort_t*)carve(3145728 * 2);
  ushort_t* wHh  = (ushort_t*)carve(4194304 * 2);
  ushort_t* wPj  = (ushort_t*)carve(196608 * 2);
  float*    cst  = (float*)carve(262144);
  int*      flags = (int*)carve(51200);          // [<=200 steps][64 blocks]
  ushort_t* gates = (ushort_t*)carve((size_t)T * 524288);
  ushort_t* decin = (ushort_t*)carve((size_t)T * 16384);
  ushort_t* enc_c = (ushort_t*)carve((size_t)T * 65536);
  ushort_t* x1    = (ushort_t*)carve((size_t)T * 32768);
  ushort_t* x2    = (ushort_t*)carve((size_t)T * 32768);
  ushort_t* hs    = (ushort_t*)carve((size_t)(T + 1) * 131072);

  // one-time weight downcasts
  cvt_f32_bf16<<<32, 256, 0, stream>>>(preW1, wW1, 8192);
  cvt_f32_bf16<<<64, 256, 0, stream>>>(preW2, wW2, 16384);
  cvt_f32_bf16<<<3072, 256, 0, stream>>>(Wih, wIh, 786432);
  cvt_f32_bf16<<<4096, 256, 0, stream>>>(Whh, wHh, 1048576);
  cvt_f32_bf16<<<192, 256, 0, stream>>>(projW, wPj, 49152);

  hipMemsetAsync(hs, 0, 131072, stream);    // h0 = 0 (slot 0)
  hipMemsetAsync(cst, 0, 262144, stream);   // c0 = 0
  hipMemsetAsync(flags, 0, 51200, stream);  // flags start below any expect

  const int nch = 1000 / T;
  const int Mb = (T * 64) / 128;            // M-blocks per chunk (T even)

  for (int c = 0; c < nch; ++c) {
    const int t0 = c * T;

    // per-chunk input downcasts
    cvt_f32_bf16<<<(T * 8192 + 255) / 256, 256, 0, stream>>>(
        enc + (size_t)t0 * 32768, enc_c, T * 8192);
    build_decin<<<T * 8, 256, 0, stream>>>(mels, decin, t0, T * 2048);

    // prenet 1: relu(decin @ W1^T + b1) -> x1 [T*64,256]
    gemm_bt<<<dim3(Mb, 2), 256, 0, stream>>>(decin, 128, 128, nullptr, 0, 0,
                                             wW1, preb1, nullptr, x1, 256, 1, 0);
    // prenet 2: relu(x1 @ W2^T + b2) -> x2 [T*64,256]
    gemm_bt<<<dim3(Mb, 2), 256, 0, stream>>>(x1, 256, 256, nullptr, 0, 0,
                                             wW2, preb2, nullptr, x2, 256, 1, 0);
    // gates_x = [x2|enc] @ W_ih^T + b_ih + b_hh -> [T*64,4096]
    gemm_bt<<<dim3(Mb, 32), 256, 0, stream>>>(x2, 256, 256, enc_c, 512, 512,
                                              wIh, bih, bhh, gates, 4096, 0, 0);
    // recurrence: one persistent launch per chunk (flag value = c+1)
    lstm_persist<<<64, 256, 0, stream>>>(gates, wHh, hs, cst, T, flags, c + 1);

    // projection: out_chunk = [hs|enc] @ projW^T + projb (f32 out)
    gemm_bt<<<dim3(Mb, 1), 256, 0, stream>>>(hs + 65536, 1024, 1024, enc_c,
                                             512, 512, wPj, projb, nullptr,
                                             out + (size_t)t0 * 8192, 128, 0, 1);
    // carry h into slot 0 for next chunk
    if (c + 1 < nch) {
      hipMemcpyAsync(hs, hs + (size_t)T * 65536, 131072,
                     hipMemcpyDeviceToDevice, stream);
    }
  }
}

// Round 2
// 6905.946 us; speedup vs baseline: 3.4291x; 1.2072x over previous
//
#include <hip/hip_runtime.h>
#include <stdint.h>

typedef __bf16 bf16x8 __attribute__((ext_vector_type(8)));
typedef float f32x4 __attribute__((ext_vector_type(4)));
typedef unsigned short ushort_t;

__device__ __forceinline__ float b2f(ushort_t u) {
  union { unsigned int i; float f; } x; x.i = ((unsigned int)u) << 16; return x.f;
}
__device__ __forceinline__ ushort_t f2b(float f) {
  union { float f; unsigned int i; } x; x.f = f;
  unsigned int r = x.i + 0x7fffu + ((x.i >> 16) & 1u);
  return (ushort_t)(r >> 16);
}
__device__ __forceinline__ float b2f_elem(ushort4 v, int j) {
  const ushort_t u = (j == 0) ? v.x : (j == 1) ? v.y : (j == 2) ? v.z : v.w;
  return b2f(u);
}
// fast tanh: 1 - 2/(e^{2x}+1); exact saturation at +/-inf, ~1e-6 abs error.
__device__ __forceinline__ float ftanh(float x) {
  const float e2 = __expf(2.f * x);
  return 1.f - 2.f / (e2 + 1.f);
}

// ---------------------------------------------------------------------------
// f32 -> bf16 downcast, 4 elements/thread. n4 = element_count / 4.
// ---------------------------------------------------------------------------
__global__ __launch_bounds__(256) void cvt_f32_bf16(const float* __restrict__ src,
                                                    ushort_t* __restrict__ dst,
                                                    int n4)
{
  const int i = blockIdx.x * 256 + threadIdx.x;
  if (i >= n4) return;
  const float4 v = ((const float4*)src)[i];
  ushort4 o;
  o.x = f2b(v.x); o.y = f2b(v.y); o.z = f2b(v.z); o.w = f2b(v.w);
  ((ushort4*)dst)[i] = o;
}

// ---------------------------------------------------------------------------
// dec chunk (bf16 [T*64,128]) from f32 mels: row gr = t0*64+(i>>5);
// dec[gr] = (gr<64) ? 0 : bf16(mels[gr-64]). 4 elems/thread, n4 = T*2048.
// ---------------------------------------------------------------------------
__global__ __launch_bounds__(256) void build_decin(const float* __restrict__ mels,
                                                   ushort_t* __restrict__ dec,
                                                   int t0, int n4)
{
  const int i = blockIdx.x * 256 + threadIdx.x;
  if (i >= n4) return;
  const int gr = t0 * 64 + (i >> 5);
  ushort4 o;
  if (gr < 64) {
    o.x = o.y = o.z = o.w = 0;
  } else {
    const float4 v = ((const float4*)mels)[(size_t)(gr - 64) * 32 + (i & 31)];
    o.x = f2b(v.x); o.y = f2b(v.y); o.z = f2b(v.z); o.w = f2b(v.w);
  }
  ((ushort4*)dec)[i] = o;
}

// ---------------------------------------------------------------------------
// C = [A1|A2] @ B^T + bias1 + bias2 (f32 biases), optional relu.
// A,B bf16; f32 accumulate; C written bf16 (out_f32=0) or f32 (out_f32=1).
// Tiles 128x128, BK=64, 4 waves. LDS rows padded to 72 elems.
// ---------------------------------------------------------------------------
__global__ __launch_bounds__(256) void gemm_bt(
    const ushort_t* __restrict__ A1, int lda1, int K1,
    const ushort_t* __restrict__ A2, int lda2, int K2,
    const ushort_t* __restrict__ B,
    const float* __restrict__ bias1, const float* __restrict__ bias2,
    void* __restrict__ C, int ldc, int relu, int out_f32)
{
  __shared__ __align__(16) ushort_t As[128 * 72];
  __shared__ __align__(16) ushort_t Bs[128 * 72];
  const int tid = threadIdx.x;
  const int wave = tid >> 6, lane = tid & 63;
  const int bm = blockIdx.x, bn = blockIdx.y;
  const int wm = (wave & 1) * 64, wn = (wave >> 1) * 64;
  const int l15 = lane & 15, quad = lane >> 4;
  const int ldb = K1 + K2;

  f32x4 acc[4][4] = {};

  const int kb1 = K1 >> 6, kb2 = K2 >> 6;
  for (int kb = 0; kb < kb1 + kb2; ++kb) {
    const bool ph2 = (kb >= kb1);
    const ushort_t* Aptr = ph2 ? A2 : A1;
    const int lda = ph2 ? lda2 : lda1;
    const int k0 = ph2 ? ((kb - kb1) << 6) : (kb << 6);
    const int bk0 = ph2 ? (K1 + k0) : k0;

#pragma unroll
    for (int s = 0; s < 4; ++s) {
      const int ch = s * 256 + tid;
      const int row = ch >> 3, pos = ch & 7;
      const bf16x8 av = *(const bf16x8*)(Aptr + (size_t)(bm * 128 + row) * lda
                                         + k0 + pos * 8);
      *(bf16x8*)(As + row * 72 + pos * 8) = av;
      const bf16x8 bv = *(const bf16x8*)(B + (size_t)(bn * 128 + row) * ldb
                                         + bk0 + pos * 8);
      *(bf16x8*)(Bs + row * 72 + pos * 8) = bv;
    }
    __syncthreads();

#pragma unroll
    for (int ks = 0; ks < 2; ++ks) {
      bf16x8 af[4], bfr[4];
      const int c = ks * 4 + quad;
#pragma unroll
      for (int mt = 0; mt < 4; ++mt)
        af[mt] = *(const bf16x8*)(As + (wm + mt * 16 + l15) * 72 + c * 8);
#pragma unroll
      for (int nt = 0; nt < 4; ++nt)
        bfr[nt] = *(const bf16x8*)(Bs + (wn + nt * 16 + l15) * 72 + c * 8);
#pragma unroll
      for (int mt = 0; mt < 4; ++mt)
#pragma unroll
        for (int nt = 0; nt < 4; ++nt)
          acc[mt][nt] = __builtin_amdgcn_mfma_f32_16x16x32_bf16(
              af[mt], bfr[nt], acc[mt][nt], 0, 0, 0);
    }
    __syncthreads();
  }

#pragma unroll
  for (int nt = 0; nt < 4; ++nt) {
    const int n = bn * 128 + wn + nt * 16 + l15;
    float bsum = 0.f;
    if (bias1) bsum += bias1[n];
    if (bias2) bsum += bias2[n];
#pragma unroll
    for (int mt = 0; mt < 4; ++mt) {
#pragma unroll
      for (int r = 0; r < 4; ++r) {
        const int m = bm * 128 + wm + mt * 16 + quad * 4 + r;
        float v = acc[mt][nt][r] + bsum;
        if (relu) v = fmaxf(v, 0.f);
        if (out_f32) ((float*)C)[(size_t)m * ldc + n] = v;
        else         ((ushort_t*)C)[(size_t)m * ldc + n] = f2b(v);
      }
    }
  }
}

// ---------------------------------------------------------------------------
// Persistent LSTM recurrence over T steps. 64 blocks x 256 threads.
// Block nb owns d-slice ds=nb*16 of all 4 gates. K-SPLIT across waves:
// wave g computes ALL 4 gates over K-quarter [g*256, g*256+256), W slice in
// 128 VGPRs. Per step, wave g:
//   - polls ONLY its 64 producer-wave flags (blocks 16g..16g+15 x 4 waves)
//   - stages its 32KB h K-quarter into LDS with 32 back-to-back
//     global_load_lds (16B) issues -> single vmcnt(0); XOR-granule swizzle
//     applied on the global source, matching swizzled ds_read (2-way = free)
//   - 128 MFMA from LDS; cross-wave f32 reduce (aliased over dead h-LDS,
//     guarded by post-MFMA barrier); elementwise; 8B agent-scope WT store
//   - wave-local vmcnt(0) drain, then lane0 sets flags[s][nb][g] (monotonic)
// ---------------------------------------------------------------------------
__global__ __launch_bounds__(256, 1) void lstm_persist(
    const ushort_t* __restrict__ gates,  // [T*64, 4096] bf16
    const ushort_t* __restrict__ Whh,    // [4096, 1024] bf16
    ushort_t* __restrict__ hs,           // [(T+1)*64, 1024] bf16
    float* __restrict__ cst,             // [64, 1024] f32, persistent
    int T, int* __restrict__ flags,      // [200][64][4] int, monotonic
    int expect)                          // chunk index + 1
{
  // per-wave h staging: hq[wave][64 rows][256 cols] bf16 = 4 x 32KB = 128KB
  __shared__ __align__(16) ushort_t hq[4 * 64 * 256];
  // reduce scratch aliased over hq (dead between post-MFMA barrier and next
  // stage): red[wave][gate-of-round][b:64][dl:17 pad] f32 = 34816B
  float* red = (float*)hq;
#define RED(w, ggl, row, col) red[(((w) * 2 + (ggl)) * 64 + (row)) * 17 + (col)]

  const int tid = threadIdx.x;
  const int g = tid >> 6, lane = tid & 63;
  const int l15 = lane & 15, quad = lane >> 4;
  const int nb = blockIdx.x;
  const int ds = nb * 16;

  // W fragments: wave g owns K-quarter [g*256, +256) for all 4 gates.
  bf16x8 warr[4][8];
#pragma unroll
  for (int gg = 0; gg < 4; ++gg) {
    const ushort_t* wrow =
        Whh + (size_t)(gg * 1024 + ds + l15) * 1024 + g * 256 + quad * 8;
#pragma unroll
    for (int ks = 0; ks < 8; ++ks)
      warr[gg][ks] = *(const bf16x8*)(wrow + ks * 32);
  }

  // c state in registers: thread owns (b = tid>>2, d = ds + (tid&3)*4 ..+4)
  const int eb = tid >> 2, edl = (tid & 3) * 4;
  f32x4 creg = *(const f32x4*)(cst + eb * 1024 + ds + edl);

  const int l5 = lane >> 5;        // stage: row parity
  const int gc = lane & 31;        // stage: granule within quarter
  const int sx = l15 & 7;          // read-side swizzle key
  ushort_t* hqg = hq + g * 16384;  // this wave's staging region (elems)

  for (int s = 0; s < T; ++s) {
    // 1. prefetch gates_x contributions (independent of h -> before poll)
    const ushort_t* gx_t =
        gates + (size_t)s * 262144 + (size_t)eb * 4096 + ds + edl;
    const ushort4 gxv0 = *(const ushort4*)(gx_t);
    const ushort4 gxv1 = *(const ushort4*)(gx_t + 1024);
    const ushort4 gxv2 = *(const ushort4*)(gx_t + 2048);
    const ushort4 gxv3 = *(const ushort4*)(gx_t + 3072);
    asm volatile("" ::: "memory");

    // 2. wait ONLY for this wave's producers: blocks 16g..16g+15, waves 0..3.
    //    flag idx = (s-1)*256 + nb*4 + w  ->  lane l: (s-1)*256 + g*64 + l.
    if (s > 0) {
      int* fp = flags + (s - 1) * 256 + g * 64 + lane;
      int v = __hip_atomic_load(fp, __ATOMIC_RELAXED, __HIP_MEMORY_SCOPE_AGENT);
      while (!__all(v == expect)) {
        __builtin_amdgcn_s_sleep(1);
        v = __hip_atomic_load(fp, __ATOMIC_RELAXED, __HIP_MEMORY_SCOPE_AGENT);
      }
      asm volatile("" ::: "memory");
    }

    // 3. stage this wave's K-quarter of h[s] into LDS: 32 x 16B/lane issues,
    //    linear LDS dest; inverse XOR-swizzle on the global source granule.
    {
      const ushort_t* hsrc = hs + (size_t)s * 65536;
#pragma unroll
      for (int i = 0; i < 32; ++i) {
        const int row = 2 * i + l5;
        const int sg = gc ^ (row & 7);
        const ushort_t* ga = hsrc + (size_t)row * 1024 + g * 256 + sg * 8;
        __builtin_amdgcn_global_load_lds(
            (const __attribute__((address_space(1))) void*)ga,
            (__attribute__((address_space(3))) void*)(hqg + i * 512),
            16, 0, 0);
      }
    }
    asm volatile("s_waitcnt vmcnt(0)" ::: "memory");  // stage (+gx) complete

    // 4. gates partial = h_quarter @ Whh_slice^T, from LDS (swizzled read)
    f32x4 acc[4][4] = {};  // [gg][mt]
#pragma unroll
    for (int ks = 0; ks < 8; ++ks) {
      const int c = ks * 4 + quad;
      bf16x8 a[4];
#pragma unroll
      for (int mt = 0; mt < 4; ++mt)
        a[mt] = *(const bf16x8*)(hqg + (mt * 16 + l15) * 256 + (c ^ sx) * 8);
#pragma unroll
      for (int gg = 0; gg < 4; ++gg)
#pragma unroll
        for (int mt = 0; mt < 4; ++mt)
          acc[gg][mt] = __builtin_amdgcn_mfma_f32_16x16x32_bf16(
              a[mt], warr[gg][ks], acc[gg][mt], 0, 0, 0);
    }
    __syncthreads();  // all waves' hq reads done -> red alias safe

    // 5. cross-wave reduce, 2 gates per round
    float gf4[4][4];
#pragma unroll
    for (int rnd = 0; rnd < 2; ++rnd) {
#pragma unroll
      for (int ggl = 0; ggl < 2; ++ggl) {
        const int gg = rnd * 2 + ggl;
#pragma unroll
        for (int mt = 0; mt < 4; ++mt)
#pragma unroll
          for (int r = 0; r < 4; ++r)
            RED(g, ggl, mt * 16 + quad * 4 + r, l15) = acc[gg][mt][r];
      }
      __syncthreads();
#pragma unroll
      for (int ggl = 0; ggl < 2; ++ggl)
#pragma unroll
        for (int j = 0; j < 4; ++j)
          gf4[rnd * 2 + ggl][j] =
              RED(0, ggl, eb, edl + j) + RED(1, ggl, eb, edl + j) +
              RED(2, ggl, eb, edl + j) + RED(3, ggl, eb, edl + j);
      if (rnd == 0) __syncthreads();  // guard buffer reuse for round 1
    }

    // 6. cell update (c in regs) + h slice store (write-through, agent scope)
    ushort_t* hdst = hs + (size_t)(s + 1) * 65536 + eb * 1024 + ds + edl;
    union { ushort_t u[4]; unsigned long long ll; } pk;
#pragma unroll
    for (int j = 0; j < 4; ++j) {
      const float gi = gf4[0][j] + b2f_elem(gxv0, j);
      const float gf = gf4[1][j] + b2f_elem(gxv1, j);
      const float gc_ = gf4[2][j] + b2f_elem(gxv2, j);
      const float go = gf4[3][j] + b2f_elem(gxv3, j);
      const float si = 1.f / (1.f + __expf(-gi));
      const float sf = 1.f / (1.f + __expf(-gf));
      const float so = 1.f / (1.f + __expf(-go));
      const float cn = sf * creg[j] + si * ftanh(gc_);
      creg[j] = cn;
      pk.u[j] = f2b(so * ftanh(cn));
    }
    __hip_atomic_store((unsigned long long*)hdst, pk.ll,
                       __ATOMIC_RELAXED, __HIP_MEMORY_SCOPE_AGENT);

    // 7. publish per-wave: wave-local drain, then one flag store (no barrier
    //    on the publish path).
    asm volatile("s_waitcnt vmcnt(0)" ::: "memory");
    if (lane == 0)
      __hip_atomic_store(flags + s * 256 + nb * 4 + g, expect,
                         __ATOMIC_RELAXED, __HIP_MEMORY_SCOPE_AGENT);
    __syncthreads();  // red reads done before next step's stage/red writes
  }

  *(f32x4*)(cst + eb * 1024 + ds + edl) = creg;  // persist c (kernel-end flush)
#undef RED
}

extern "C" void kernel_launch(void* const* d_in, const int* in_sizes, int n_in,
                              void* d_out, int out_size, void* d_ws, size_t ws_size,
                              hipStream_t stream) {
  // All inputs are float32 (reference dtype); internal compute is bf16.
  const float* enc   = (const float*)d_in[0];   // [1000,64,512]
  const float* mels  = (const float*)d_in[1];   // [1000,64,128]
  const float* preW1 = (const float*)d_in[2];   // [256,128]
  const float* preb1 = (const float*)d_in[3];
  const float* preW2 = (const float*)d_in[4];   // [256,256]
  const float* preb2 = (const float*)d_in[5];
  const float* Wih   = (const float*)d_in[6];   // [4096,768]
  const float* Whh   = (const float*)d_in[7];   // [4096,1024]
  const float* bih   = (const float*)d_in[8];
  const float* bhh   = (const float*)d_in[9];
  const float* projW = (const float*)d_in[10];  // [128,1536]
  const float* projb = (const float*)d_in[11];
  float* out = (float*)d_out;                   // [1000,64,128] f32

  // chunk length T: largest even divisor of 1000 whose buffers fit ws_size
  const size_t fixedB = 32768 * 2 + 65536 * 2 + 3145728 * 2 + 4194304 * 2
                      + 196608 * 2 + 262144 + 204800 + 65536;  // weights+cst+flags+slack
  const int cand[5] = {200, 100, 50, 10, 2};
  int T = 2;
  for (int ci = 0; ci < 5; ++ci) {
    const int t = cand[ci];
    size_t need = fixedB
                + (size_t)t * 524288            // gates bf16 [T*64,4096]
                + (size_t)t * 16384             // decin bf16 [T*64,128]
                + (size_t)t * 65536             // enc_c bf16 [T*64,512]
                + (size_t)t * 32768 * 2         // x1,x2 bf16 [T*64,256]
                + (size_t)(t + 1) * 131072;     // hs bf16 [(T+1)*64,1024]
    if (need <= ws_size) { T = t; break; }
  }

  char* ws = (char*)d_ws;
  size_t off = 0;
  auto carve = [&](size_t bytes) {
    char* p = ws + off;
    off += (bytes + 255) & ~(size_t)255;
    return p;
  };
  ushort_t* wW1  = (ushort_t*)carve(32768 * 2);
  ushort_t* wW2  = (ushort_t*)carve(65536 * 2);
  ushort_t* wIh  = (ushort_t*)carve(3145728 * 2);
  ushort_t* wHh  = (ushort_t*)carve(4194304 * 2);
  ushort_t* wPj  = (ushort_t*)carve(196608 * 2);
  float*    cst  = (float*)carve(262144);
  int*      flags = (int*)carve(204800);         // [200 steps][64 blocks][4 waves]
  ushort_t* gates = (ushort_t*)carve((size_t)T * 524288);
  ushort_t* decin = (ushort_t*)carve((size_t)T * 16384);
  ushort_t* enc_c = (ushort_t*)carve((size_t)T * 65536);
  ushort_t* x1    = (ushort_t*)carve((size_t)T * 32768);
  ushort_t* x2    = (ushort_t*)carve((size_t)T * 32768);
  ushort_t* hs    = (ushort_t*)carve((size_t)(T + 1) * 131072);

  // one-time weight downcasts
  cvt_f32_bf16<<<32, 256, 0, stream>>>(preW1, wW1, 8192);
  cvt_f32_bf16<<<64, 256, 0, stream>>>(preW2, wW2, 16384);
  cvt_f32_bf16<<<3072, 256, 0, stream>>>(Wih, wIh, 786432);
  cvt_f32_bf16<<<4096, 256, 0, stream>>>(Whh, wHh, 1048576);
  cvt_f32_bf16<<<192, 256, 0, stream>>>(projW, wPj, 49152);

  hipMemsetAsync(hs, 0, 131072, stream);    // h0 = 0 (slot 0)
  hipMemsetAsync(cst, 0, 262144, stream);   // c0 = 0
  hipMemsetAsync(flags, 0, 204800, stream); // flags start below any expect

  const int nch = 1000 / T;
  const int Mb = (T * 64) / 128;            // M-blocks per chunk (T even)

  for (int c = 0; c < nch; ++c) {
    const int t0 = c * T;

    // per-chunk input downcasts
    cvt_f32_bf16<<<(T * 8192 + 255) / 256, 256, 0, stream>>>(
        enc + (size_t)t0 * 32768, enc_c, T * 8192);
    build_decin<<<T * 8, 256, 0, stream>>>(mels, decin, t0, T * 2048);

    // prenet 1: relu(decin @ W1^T + b1) -> x1 [T*64,256]
    gemm_bt<<<dim3(Mb, 2), 256, 0, stream>>>(decin, 128, 128, nullptr, 0, 0,
                                             wW1, preb1, nullptr, x1, 256, 1, 0);
    // prenet 2: relu(x1 @ W2^T + b2) -> x2 [T*64,256]
    gemm_bt<<<dim3(Mb, 2), 256, 0, stream>>>(x1, 256, 256, nullptr, 0, 0,
                                             wW2, preb2, nullptr, x2, 256, 1, 0);
    // gates_x = [x2|enc] @ W_ih^T + b_ih + b_hh -> [T*64,4096]
    gemm_bt<<<dim3(Mb, 32), 256, 0, stream>>>(x2, 256, 256, enc_c, 512, 512,
                                              wIh, bih, bhh, gates, 4096, 0, 0);
    // recurrence: one persistent launch per chunk (flag value = c+1)
    lstm_persist<<<64, 256, 0, stream>>>(gates, wHh, hs, cst, T, flags, c + 1);

    // projection: out_chunk = [hs|enc] @ projW^T + projb (f32 out)
    gemm_bt<<<dim3(Mb, 1), 256, 0, stream>>>(hs + 65536, 1024, 1024, enc_c,
                                             512, 512, wPj, projb, nullptr,
                                             out + (size_t)t0 * 8192, 128, 0, 1);
    // carry h into slot 0 for next chunk
    if (c + 1 < nch) {
      hipMemcpyAsync(hs, hs + (size_t)T * 65536, 131072,
                     hipMemcpyDeviceToDevice, stream);
    }
  }
}